// Round 24
// baseline (391.470 us; speedup 1.0000x reference)
//
#include <hip/hip_runtime.h>
#include <stdint.h>

// Problem constants
#define M_TOT 8192      // B*N = 4*2048 rows
#define N_TOT 16384     // out_dim = 2*128*64
#define K_TOT 1024      // HIDDEN

typedef __bf16 bf16x8 __attribute__((ext_vector_type(8)));
typedef float f32x4 __attribute__((ext_vector_type(4)));
typedef float f32x16 __attribute__((ext_vector_type(16)));

__device__ __forceinline__ unsigned short f2bf(float f) {
  unsigned int u = __float_as_uint(f);
  u = u + 0x7FFFu + ((u >> 16) & 1u);   // RNE
  return (unsigned short)(u >> 16);
}

__device__ __forceinline__ void gload_lds16(const void* g, void* l) {
  __builtin_amdgcn_global_load_lds(
      (const __attribute__((address_space(1))) unsigned int*)g,
      (__attribute__((address_space(3))) unsigned int*)l,
      16, 0, 0);
}

// ---- prep kernel 1: node f32 -> bf16, nt loads (read-once) ----
__global__ __launch_bounds__(256) void k_convert_node(
    const float* __restrict__ src, unsigned short* __restrict__ dst) {
  size_t i0 = ((size_t)blockIdx.x * 256 + threadIdx.x) * 8;
#pragma unroll
  for (int it = 0; it < 2; it++) {
    size_t i = i0 + (size_t)it * (2048 * 256 * 8);
    f32x4 v0 = __builtin_nontemporal_load((const f32x4*)(src + i));
    f32x4 v1 = __builtin_nontemporal_load((const f32x4*)(src + i + 4));
    union { unsigned short u[8]; uint4 q; } r;
    r.u[0] = f2bf(v0[0]); r.u[1] = f2bf(v0[1]); r.u[2] = f2bf(v0[2]); r.u[3] = f2bf(v0[3]);
    r.u[4] = f2bf(v1[0]); r.u[5] = f2bf(v1[1]); r.u[6] = f2bf(v1[2]); r.u[7] = f2bf(v1[3]);
    *(uint4*)(dst + i) = r.q;
  }
}

// ---- prep kernel 2: W [K][O] f32 -> Wt [O][K] bf16, write-phase transpose ----
__global__ __launch_bounds__(256) void k_transpose_w(
    const float* __restrict__ W, unsigned short* __restrict__ Wt) {
  __shared__ float tileT[64][68];   // [o][k] — already transposed
  int o0 = blockIdx.x * 64;
  int k0 = blockIdx.y * 64;
  int t = threadIdx.x;
  int kr0 = t >> 4, c4 = t & 15;
#pragma unroll
  for (int i = 0; i < 4; i++) {
    int kr = kr0 + i * 16;
    f32x4 v = __builtin_nontemporal_load(
        (const f32x4*)&W[(size_t)(k0 + kr) * N_TOT + o0 + c4 * 4]);
    tileT[c4 * 4 + 0][kr] = v[0];
    tileT[c4 * 4 + 1][kr] = v[1];
    tileT[c4 * 4 + 2][kr] = v[2];
    tileT[c4 * 4 + 3][kr] = v[3];
  }
  __syncthreads();
  int or0 = t >> 3, c8 = t & 7;
#pragma unroll
  for (int i = 0; i < 2; i++) {
    int orr = or0 + i * 32;
    float4 a = *(const float4*)&tileT[orr][c8 * 8];
    float4 b = *(const float4*)&tileT[orr][c8 * 8 + 4];
    union { unsigned short u[8]; uint4 q; } r;
    r.u[0] = f2bf(a.x); r.u[1] = f2bf(a.y); r.u[2] = f2bf(a.z); r.u[3] = f2bf(a.w);
    r.u[4] = f2bf(b.x); r.u[5] = f2bf(b.y); r.u[6] = f2bf(b.z); r.u[7] = f2bf(b.w);
    *(uint4*)&Wt[(size_t)(o0 + orr) * K_TOT + k0 + c8 * 8] = r.q;
  }
}

// ---- prep kernel 3: sin/cos tables [row=8192][d=32] ----
__global__ __launch_bounds__(256) void k_sincos(
    const float* __restrict__ mass, float* __restrict__ sin_t, float* __restrict__ cos_t) {
  int t = blockIdx.x * 256 + threadIdx.x;   // 0..262143
  int row = t >> 5;
  int d = t & 31;
  float m = mass[row];
  float invf = expf(-0.28782313662425575f * (float)d);  // ln(10000)/32
  float ang = m * invf;
  float s, c;
  sincosf(ang, &s, &c);
  sin_t[t] = s;
  cos_t[t] = c;
}

// ---- main GEMM: r17 base (256x128, BK=32, 4 waves, 3-deep LDS, vmcnt(6),
//      2 blocks/CU, T2 swizzle, L2 superblock swizzle, nt stores) with ONE
//      change: 32x32x16 MFMA. 16 issues/iter (was 32), 2 barriers/iter
//      (was 3), +15% MFMA ceiling. Per wave: 4Mx2N tiles of 32x32,
//      acc[4][2] f32x16. C/D: col=lane&31, row=(reg&3)+8*(reg>>2)+
//      4*(lane>>5) [m74/m101]. A/B frag: row=lane&31, k-chunk=lane>>5. ----
__global__ __launch_bounds__(256, 2) void k_gemm256b(
    const unsigned short* __restrict__ A,    // [8192][1024] bf16
    const unsigned short* __restrict__ Bt,   // [16384][1024] bf16 (W^T)
    const float* __restrict__ bias,          // [16384]
    const float* __restrict__ sin_t,         // [8192][32]
    const float* __restrict__ cos_t,
    float* __restrict__ out)                 // [2][4][128][2048][64]
{
  extern __shared__ char smem[];   // 3 bufs x (As 16KB + Bs 8KB) = 72 KiB

  int tid  = threadIdx.x;
  int lane = tid & 63;
  int wid  = tid >> 6;      // 0..3
  int wm   = wid >> 1;      // 0..1  (M half: 128 rows)
  int wn   = wid & 1;       // 0..1  (N half: 64 cols)

  // L2-locality superblock swizzle (bijective; 4096 blocks, 4096 % 8 == 0):
  int orig = blockIdx.x;
  int x   = orig & 7;
  int c   = orig >> 3;
  int st  = c >> 5;
  int w   = c & 31;
  int bm0 = (x * 4 + (w >> 3)) * 256;    // bm index: 4x + 0..3   (32 total)
  int bn0 = (st * 8 + (w & 7)) * 128;    // bn index: 8*st + 0..7 (128 total)

  // staging with inverse-swizzled source (T2 both-sides, rule #21):
  int sv   = (tid & 7) ^ ((tid >> 3) & 7);
  int arow = ((tid >> 3) << 1) + (sv >> 2);
  int kst  = sv & 3;
  const unsigned short* srcA = A  + (size_t)(bm0 + arow) * K_TOT + kst * 8;
  const unsigned short* srcB = Bt + (size_t)(bn0 + arow) * K_TOT + kst * 8;
  const size_t rs64 = (size_t)64 * K_TOT;

  int wofs = wid * 1024;

#define STAGE_A(s_, bo_) do { char* dA = smem + (bo_) + wofs; \
    const unsigned short* sa = srcA + (size_t)(s_) * 32; \
    gload_lds16(sa,            dA); \
    gload_lds16(sa + rs64,     dA + 4096); \
    gload_lds16(sa + 2 * rs64, dA + 8192); \
    gload_lds16(sa + 3 * rs64, dA + 12288); } while (0)
#define STAGE_B(s_, bo_) do { char* dB = smem + (bo_) + 16384 + wofs; \
    const unsigned short* sb = srcB + (size_t)(s_) * 32; \
    gload_lds16(sb,        dB); \
    gload_lds16(sb + rs64, dB + 4096); } while (0)

  // prologue: prefetch K-tiles 0,1 (12 loads in flight per wave)
  STAGE_A(0, 0); STAGE_B(0, 0);
  STAGE_A(1, 24576); STAGE_B(1, 24576);

  f32x16 acc[4][2] = {};

  int r32 = lane & 31;      // row within 32-row tile
  int hk  = lane >> 5;      // k-chunk half (0/1)
  int srow = r32 >> 1;
  int sxor = srow & 7;
  int rodd4 = (r32 & 1) << 2;
  // swizzled slot for 8-bf16 k-slot ks: v = (rodd4 + ks) ^ sxor
  // A tile (mi, kk): base wm*8192 + mi*2048 + srow*128 + v(kk*2+hk)*16
  // B tile (ni, kk): 16384 + wn*4096 + ni*2048 + srow*128 + v(kk*2+hk)*16

  int cur = 0;              // buf byte offsets rotate 0 -> 24576 -> 49152
  int stg = 49152;          // stage target for tile s+2 = buf (s-1)%3

  for (int s = 0; s < 32; ++s) {
    if (s < 31) { asm volatile("s_waitcnt vmcnt(6)" ::: "memory"); }
    else        { asm volatile("s_waitcnt vmcnt(0)" ::: "memory"); }
    __builtin_amdgcn_s_barrier();          // tile s resident for ALL waves
    __builtin_amdgcn_sched_barrier(0);     // keep ds_reads below the barrier

    const char* As_ = smem + cur;
    const char* Bs_ = As_ + 16384;

    // ---- single phase: {12 ds_reads, stage A+B(s+2)} -> barrier ->
    //      lgkmcnt(0) -> 16-MFMA cluster ----
    bf16x8 aF[4][2], bF[2][2];
#pragma unroll
    for (int mi = 0; mi < 4; mi++)
#pragma unroll
      for (int kk = 0; kk < 2; kk++)
        aF[mi][kk] = *(const bf16x8*)(As_ + wm * 8192 + mi * 2048 + srow * 128
                                      + (((rodd4 + kk * 2 + hk) ^ sxor) << 4));
#pragma unroll
    for (int ni = 0; ni < 2; ni++)
#pragma unroll
      for (int kk = 0; kk < 2; kk++)
        bF[ni][kk] = *(const bf16x8*)(Bs_ + wn * 4096 + ni * 2048 + srow * 128
                                      + (((rodd4 + kk * 2 + hk) ^ sxor) << 4));
    if (s < 30) { STAGE_A(s + 2, stg); STAGE_B(s + 2, stg); }
    __builtin_amdgcn_sched_barrier(0);     // pin reads+stage above the barrier
    __builtin_amdgcn_s_barrier();
    asm volatile("s_waitcnt lgkmcnt(0)" ::: "memory");
    __builtin_amdgcn_sched_barrier(0);
    __builtin_amdgcn_s_setprio(1);
#pragma unroll
    for (int kk = 0; kk < 2; kk++)
#pragma unroll
      for (int mi = 0; mi < 4; mi++)
#pragma unroll
        for (int ni = 0; ni < 2; ni++)
          acc[mi][ni] = __builtin_amdgcn_mfma_f32_32x32x16_bf16(
              aF[mi][kk], bF[ni][kk], acc[mi][ni], 0, 0, 0);
    __builtin_amdgcn_s_setprio(0);

    stg = cur;                                  // next stage target = buf we just read
    cur = (cur == 49152) ? 0 : cur + 24576;     // advance read buf
  }
#undef STAGE_A
#undef STAGE_B

  // ---- fused epilogue: bias + RoPE (K half) + transposed NONTEMPORAL
  //      scatter. C/D map: col=lane&31, row=(j&3)+8*(j>>2)+4*hk. ----
  float bv0 = bias[bn0 + wn * 64 + r32];
  float bv1 = bias[bn0 + wn * 64 + 32 + r32];

  int cgrp = (bn0 >> 6) + wn;          // head-channel index 0..255, wave-uniform
  int is_k = (cgrp < 128);
  int h = cgrp & 127;
  size_t sec = is_k ? 0 : 4;           // s*4 (s=0 for K, 1 for V)

#pragma unroll
  for (int mi = 0; mi < 4; mi++) {
#pragma unroll
    for (int j = 0; j < 16; j++) {
      int row = bm0 + wm * 128 + mi * 32 + (j & 3) + ((j >> 2) << 3) + (hk << 2);
      int bb = row >> 11;
      int n  = row & 2047;
      float* op = out + (((sec + bb) * 128 + h) * 2048 + (size_t)n) * 64;
      if (is_k) {
        float x0 = acc[mi][0][j] + bv0;
        float x1 = acc[mi][1][j] + bv1;
        float sv2 = sin_t[row * 32 + r32];
        float cv2 = cos_t[row * 32 + r32];
        __builtin_nontemporal_store(x0 * cv2 - x1 * sv2, op + r32);
        __builtin_nontemporal_store(x0 * sv2 + x1 * cv2, op + r32 + 32);
      } else {
        __builtin_nontemporal_store(acc[mi][0][j] + bv0, op + r32);
        __builtin_nontemporal_store(acc[mi][1][j] + bv1, op + r32 + 32);
      }
    }
  }
}

extern "C" void kernel_launch(void* const* d_in, const int* in_sizes, int n_in,
                              void* d_out, int out_size, void* d_ws, size_t ws_size,
                              hipStream_t stream) {
  const float* node = (const float*)d_in[0];   // [4][2048][1024]
  const float* mass = (const float*)d_in[1];   // [4][2048]
  const float* W    = (const float*)d_in[2];   // [1024][16384]
  const float* bias = (const float*)d_in[3];   // [16384]
  float* out = (float*)d_out;

  // workspace layout
  const size_t NODE_B  = (size_t)M_TOT * K_TOT * 2;       // 16.78 MB
  const size_t WT_B    = (size_t)N_TOT * K_TOT * 2;       // 33.55 MB
  const size_t SIN_B   = (size_t)M_TOT * 32 * 4;          // 1.05 MB
  if (ws_size < NODE_B + WT_B + 2 * SIN_B) return;        // fail visibly

  char* ws = (char*)d_ws;
  unsigned short* nodeB = (unsigned short*)ws;
  unsigned short* WtB   = (unsigned short*)(ws + NODE_B);
  float* sin_t = (float*)(ws + NODE_B + WT_B);
  float* cos_t = (float*)(ws + NODE_B + WT_B + SIN_B);

  // allow 72 KiB dynamic LDS for the GEMM (2 blocks/CU: 2 x 72 <= 160 KiB)
  (void)hipFuncSetAttribute((const void*)k_gemm256b,
                            hipFuncAttributeMaxDynamicSharedMemorySize, 73728);

  k_convert_node<<<2048, 256, 0, stream>>>(node, nodeB);
  k_transpose_w<<<dim3(N_TOT / 64, K_TOT / 64), 256, 0, stream>>>(W, WtB);
  k_sincos<<<(M_TOT * 32) / 256, 256, 0, stream>>>(mass, sin_t, cos_t);
  k_gemm256b<<<dim3((M_TOT / 256) * (N_TOT / 128)), dim3(256), 73728, stream>>>(
      nodeB, WtB, bias, sin_t, cos_t, out);
}

// Round 25
// 327.150 us; speedup vs baseline: 1.1966x; 1.1966x over previous
//
#include <hip/hip_runtime.h>
#include <stdint.h>

// Problem constants
#define M_TOT 8192      // B*N = 4*2048 rows
#define N_TOT 16384     // out_dim = 2*128*64
#define K_TOT 1024      // HIDDEN

typedef __bf16 bf16x8 __attribute__((ext_vector_type(8)));
typedef float f32x4 __attribute__((ext_vector_type(4)));

__device__ __forceinline__ unsigned short f2bf(float f) {
  unsigned int u = __float_as_uint(f);
  u = u + 0x7FFFu + ((u >> 16) & 1u);   // RNE
  return (unsigned short)(u >> 16);
}

__device__ __forceinline__ void gload_lds16(const void* g, void* l) {
  __builtin_amdgcn_global_load_lds(
      (const __attribute__((address_space(1))) unsigned int*)g,
      (__attribute__((address_space(3))) unsigned int*)l,
      16, 0, 0);
}

// ---- prep kernel 1: node f32 -> bf16, 32 elems/thread, 1024 blocks ----
__global__ __launch_bounds__(256) void k_convert_node(
    const float* __restrict__ src, unsigned short* __restrict__ dst) {
  size_t base = ((size_t)blockIdx.x * 256 + threadIdx.x) * 8;
#pragma unroll
  for (int it = 0; it < 4; it++) {
    size_t i = base + (size_t)it * (1024 * 256 * 8);
    float4 v0 = *(const float4*)(src + i);
    float4 v1 = *(const float4*)(src + i + 4);
    union { unsigned short u[8]; uint4 q; } r;
    r.u[0] = f2bf(v0.x); r.u[1] = f2bf(v0.y); r.u[2] = f2bf(v0.z); r.u[3] = f2bf(v0.w);
    r.u[4] = f2bf(v1.x); r.u[5] = f2bf(v1.y); r.u[6] = f2bf(v1.z); r.u[7] = f2bf(v1.w);
    *(uint4*)(dst + i) = r.q;
  }
}

// ---- prep kernel 2: W [K][O] f32 -> Wt [O][K] bf16, 64x64 tiles ----
__global__ __launch_bounds__(256) void k_transpose_w(
    const float* __restrict__ W, unsigned short* __restrict__ Wt) {
  __shared__ float tile[64][65];
  int o0 = blockIdx.x * 64;
  int k0 = blockIdx.y * 64;
  int t = threadIdx.x;
  int kr0 = t >> 4, c4 = t & 15;
#pragma unroll
  for (int i = 0; i < 4; i++) {
    int kr = kr0 + i * 16;
    float4 v = *(const float4*)&W[(size_t)(k0 + kr) * N_TOT + o0 + c4 * 4];
    tile[kr][c4 * 4 + 0] = v.x;
    tile[kr][c4 * 4 + 1] = v.y;
    tile[kr][c4 * 4 + 2] = v.z;
    tile[kr][c4 * 4 + 3] = v.w;
  }
  __syncthreads();
  int or0 = t >> 3, c8 = t & 7;
#pragma unroll
  for (int i = 0; i < 2; i++) {
    int orr = or0 + i * 32;
    union { unsigned short u[8]; uint4 q; } r;
#pragma unroll
    for (int j = 0; j < 8; j++) r.u[j] = f2bf(tile[c8 * 8 + j][orr]);
    *(uint4*)&Wt[(size_t)(o0 + orr) * K_TOT + k0 + c8 * 8] = r.q;
  }
}

// ---- prep kernel 3: sin/cos tables [row=8192][d=32] ----
__global__ __launch_bounds__(256) void k_sincos(
    const float* __restrict__ mass, float* __restrict__ sin_t, float* __restrict__ cos_t) {
  int t = blockIdx.x * 256 + threadIdx.x;   // 0..262143
  int row = t >> 5;
  int d = t & 31;
  float m = mass[row];
  float invf = expf(-0.28782313662425575f * (float)d);  // ln(10000)/32
  float ang = m * invf;
  float s, c;
  sincosf(ang, &s, &c);
  sin_t[t] = s;
  cos_t[t] = c;
}

// ---- main GEMM: 256x128 tile, BK=32, 4 waves (2x2), 3-deep pipelined LDS,
//      counted vmcnt(6), 2 blocks/CU, conflict-free LDS swizzle (T2),
//      L2-locality superblock XCD swizzle, barrier-paired phases,
//      NONTEMPORAL epilogue stores. Best-verified configuration (r17). ----
__global__ __launch_bounds__(256, 2) void k_gemm256b(
    const unsigned short* __restrict__ A,    // [8192][1024] bf16
    const unsigned short* __restrict__ Bt,   // [16384][1024] bf16 (W^T)
    const float* __restrict__ bias,          // [16384]
    const float* __restrict__ sin_t,         // [8192][32]
    const float* __restrict__ cos_t,
    float* __restrict__ out)                 // [2][4][128][2048][64]
{
  extern __shared__ char smem[];   // 3 bufs x (As 16KB + Bs 8KB) = 72 KiB

  int tid  = threadIdx.x;
  int lane = tid & 63;
  int wid  = tid >> 6;      // 0..3
  int wm   = wid >> 1;      // 0..1  (M half: 128 rows)
  int wn   = wid & 1;       // 0..1  (N half: 64 cols)

  // L2-locality superblock swizzle (bijective; 4096 blocks, 4096 % 8 == 0):
  int orig = blockIdx.x;
  int x   = orig & 7;
  int c   = orig >> 3;
  int st  = c >> 5;
  int w   = c & 31;
  int bm0 = (x * 4 + (w >> 3)) * 256;    // bm index: 4x + 0..3   (32 total)
  int bn0 = (st * 8 + (w & 7)) * 128;    // bn index: 8*st + 0..7 (128 total)

  // staging with inverse-swizzled source (T2 both-sides, rule #21):
  int sv   = (tid & 7) ^ ((tid >> 3) & 7);
  int arow = ((tid >> 3) << 1) + (sv >> 2);
  int kst  = sv & 3;
  const unsigned short* srcA = A  + (size_t)(bm0 + arow) * K_TOT + kst * 8;
  const unsigned short* srcB = Bt + (size_t)(bn0 + arow) * K_TOT + kst * 8;
  const size_t rs64 = (size_t)64 * K_TOT;

  // wave-uniform LDS staging bases: A at buf+0 (16KB), B at buf+16384 (8KB)
  int wofs = wid * 1024;

#define STAGE_A(s_, bo_) do { char* dA = smem + (bo_) + wofs; \
    const unsigned short* sa = srcA + (size_t)(s_) * 32; \
    gload_lds16(sa,            dA); \
    gload_lds16(sa + rs64,     dA + 4096); \
    gload_lds16(sa + 2 * rs64, dA + 8192); \
    gload_lds16(sa + 3 * rs64, dA + 12288); } while (0)
#define STAGE_B(s_, bo_) do { char* dB = smem + (bo_) + 16384 + wofs; \
    const unsigned short* sb = srcB + (size_t)(s_) * 32; \
    gload_lds16(sb,        dB); \
    gload_lds16(sb + rs64, dB + 4096); } while (0)

  // prologue: prefetch K-tiles 0,1 (12 loads in flight per wave)
  STAGE_A(0, 0); STAGE_B(0, 0);
  STAGE_A(1, 24576); STAGE_B(1, 24576);

  f32x4 acc[8][4] = {};

  int r = lane & 15;        // frag row/col within 16
  int q = lane >> 4;        // k-chunk 0..3 (8 bf16 each)
  int sl   = (((r & 1) << 2) + q) ^ ((r >> 1) & 7);
  int aoff = wm * 8192 + (r >> 1) * 128 + sl * 16;   // byte offset in As
  int boff = wn * 4096 + (r >> 1) * 128 + sl * 16;   // byte offset in Bs

  int cur = 0;              // buf byte offsets rotate 0 -> 24576 -> 49152
  int stg = 49152;          // stage target for tile s+2 = buf (s-1)%3

  for (int s = 0; s < 32; ++s) {
    if (s < 31) { asm volatile("s_waitcnt vmcnt(6)" ::: "memory"); }
    else        { asm volatile("s_waitcnt vmcnt(0)" ::: "memory"); }
    __builtin_amdgcn_s_barrier();          // tile s resident for ALL waves
    __builtin_amdgcn_sched_barrier(0);     // keep ds_reads below the barrier

    const char* As_ = smem + cur;
    const char* Bs_ = As_ + 16384;

    // ---- phase 0: {B frags + A frags (m 0..3), stage A(s+2)} -> barrier
    //      -> lgkmcnt(0) -> MFMA cluster ----
    bf16x8 bfrag[4], afrag[4];
#pragma unroll
    for (int ni = 0; ni < 4; ni++) bfrag[ni] = *(const bf16x8*)(Bs_ + boff + ni * 1024);
#pragma unroll
    for (int mi = 0; mi < 4; mi++) afrag[mi] = *(const bf16x8*)(As_ + aoff + mi * 1024);
    if (s < 30) STAGE_A(s + 2, stg);
    __builtin_amdgcn_sched_barrier(0);     // pin reads+stage above the barrier
    __builtin_amdgcn_s_barrier();
    asm volatile("s_waitcnt lgkmcnt(0)" ::: "memory");
    __builtin_amdgcn_sched_barrier(0);
    __builtin_amdgcn_s_setprio(1);
#pragma unroll
    for (int mi = 0; mi < 4; mi++)
#pragma unroll
      for (int ni = 0; ni < 4; ni++)
        acc[mi][ni] = __builtin_amdgcn_mfma_f32_16x16x32_bf16(afrag[mi], bfrag[ni], acc[mi][ni], 0, 0, 0);
    __builtin_amdgcn_s_setprio(0);

    // ---- phase 1: {A frags (m 4..7), stage B(s+2)} -> barrier
    //      -> lgkmcnt(0) -> MFMA cluster ----
    bf16x8 afrag2[4];
#pragma unroll
    for (int mi = 0; mi < 4; mi++) afrag2[mi] = *(const bf16x8*)(As_ + aoff + (mi + 4) * 1024);
    if (s < 30) STAGE_B(s + 2, stg);
    __builtin_amdgcn_sched_barrier(0);     // pin reads+stage above the barrier
    __builtin_amdgcn_s_barrier();
    asm volatile("s_waitcnt lgkmcnt(0)" ::: "memory");
    __builtin_amdgcn_sched_barrier(0);
    __builtin_amdgcn_s_setprio(1);
#pragma unroll
    for (int mi = 0; mi < 4; mi++)
#pragma unroll
      for (int ni = 0; ni < 4; ni++)
        acc[mi + 4][ni] = __builtin_amdgcn_mfma_f32_16x16x32_bf16(afrag2[mi], bfrag[ni], acc[mi + 4][ni], 0, 0, 0);
    __builtin_amdgcn_s_setprio(0);

    stg = cur;                                  // next stage target = buf we just read
    cur = (cur == 49152) ? 0 : cur + 24576;     // advance read buf
  }
#undef STAGE_A
#undef STAGE_B

  // ---- fused epilogue: bias + RoPE (K half) + transposed NONTEMPORAL
  //      scatter (nt stores bypass L2/L3 — output is never re-read) ----
  int col16 = r;
  float bv[4];
#pragma unroll
  for (int ni = 0; ni < 4; ni++) bv[ni] = bias[bn0 + wn * 64 + ni * 16 + col16];

  int cgrp = (bn0 >> 6) + wn;          // head-channel index 0..255, wave-uniform
  int is_k = (cgrp < 128);
  int h = cgrp & 127;
  size_t sec = is_k ? 0 : 4;           // s*4 (s=0 for K, 1 for V)

#pragma unroll
  for (int mi = 0; mi < 8; mi++) {
#pragma unroll
    for (int reg = 0; reg < 4; reg++) {
      int row = bm0 + wm * 128 + mi * 16 + q * 4 + reg;
      int bb = row >> 11;
      int n  = row & 2047;
      float* op = out + (((sec + bb) * 128 + h) * 2048 + (size_t)n) * 64;
      if (is_k) {
#pragma unroll
        for (int ni = 0; ni < 2; ni++) {
          int d = ni * 16 + col16;               // d in [0,32)
          float x0 = acc[mi][ni][reg]     + bv[ni];
          float x1 = acc[mi][ni + 2][reg] + bv[ni + 2];
          float sv2 = sin_t[row * 32 + d];
          float cv2 = cos_t[row * 32 + d];
          __builtin_nontemporal_store(x0 * cv2 - x1 * sv2, op + d);
          __builtin_nontemporal_store(x0 * sv2 + x1 * cv2, op + d + 32);
        }
      } else {
#pragma unroll
        for (int ni = 0; ni < 4; ni++) {
          int d = ni * 16 + col16;
          __builtin_nontemporal_store(acc[mi][ni][reg] + bv[ni], op + d);
        }
      }
    }
  }
}

extern "C" void kernel_launch(void* const* d_in, const int* in_sizes, int n_in,
                              void* d_out, int out_size, void* d_ws, size_t ws_size,
                              hipStream_t stream) {
  const float* node = (const float*)d_in[0];   // [4][2048][1024]
  const float* mass = (const float*)d_in[1];   // [4][2048]
  const float* W    = (const float*)d_in[2];   // [1024][16384]
  const float* bias = (const float*)d_in[3];   // [16384]
  float* out = (float*)d_out;

  // workspace layout
  const size_t NODE_B  = (size_t)M_TOT * K_TOT * 2;       // 16.78 MB
  const size_t WT_B    = (size_t)N_TOT * K_TOT * 2;       // 33.55 MB
  const size_t SIN_B   = (size_t)M_TOT * 32 * 4;          // 1.05 MB
  if (ws_size < NODE_B + WT_B + 2 * SIN_B) return;        // fail visibly

  char* ws = (char*)d_ws;
  unsigned short* nodeB = (unsigned short*)ws;
  unsigned short* WtB   = (unsigned short*)(ws + NODE_B);
  float* sin_t = (float*)(ws + NODE_B + WT_B);
  float* cos_t = (float*)(ws + NODE_B + WT_B + SIN_B);

  // allow 72 KiB dynamic LDS for the GEMM (2 blocks/CU: 2 x 72 <= 160 KiB)
  (void)hipFuncSetAttribute((const void*)k_gemm256b,
                            hipFuncAttributeMaxDynamicSharedMemorySize, 73728);

  k_convert_node<<<1024, 256, 0, stream>>>(node, nodeB);
  k_transpose_w<<<dim3(N_TOT / 64, K_TOT / 64), 256, 0, stream>>>(W, WtB);
  k_sincos<<<(M_TOT * 32) / 256, 256, 0, stream>>>(mass, sin_t, cos_t);
  k_gemm256b<<<dim3((M_TOT / 256) * (N_TOT / 128)), dim3(256), 73728, stream>>>(
      nodeB, WtB, bias, sin_t, cos_t, out);
}